// Round 1
// baseline (2589.457 us; speedup 1.0000x reference)
//
#include <hip/hip_runtime.h>

#define N_NODES 50000
#define BDIM 8
#define DDIM 64
#define ODIM 64
#define KM 5
#define BD 512          // B*D
#define W_STRIDE 68     // 64 + 4 pad (keeps float4 alignment, breaks bank conflicts)
#define Y_STRIDE 65     // 64 + 1 pad

// ---------------- transpose: x (B,N,D) -> x0 (N, B*D) ----------------
__global__ void k_transpose(const float* __restrict__ x, float* __restrict__ x0, int tot4) {
  int i = blockIdx.x * blockDim.x + threadIdx.x;
  if (i >= tot4) return;
  int f = i << 2;                 // flat index into x, multiple of 4
  int d = f & (DDIM - 1);
  int nb = f >> 6;                // b*N + n
  int b = nb / N_NODES;
  int n = nb - b * N_NODES;
  float4 v = *(const float4*)(x + (size_t)f);
  *(float4*)(x0 + (size_t)n * BD + b * DDIM + d) = v;
}

// ---------------- CSR build ----------------
__global__ void k_hist(const int* __restrict__ rows, int* __restrict__ cnt, int E) {
  int e = blockIdx.x * blockDim.x + threadIdx.x;
  if (e < E) atomicAdd(&cnt[rows[e]], 1);
}

// single block, 1024 threads: counts -> exclusive offsets (in place) + rowptr
__global__ void k_scan(int* __restrict__ cnt, int* __restrict__ rowptr, int n) {
  __shared__ int lsum[1024];
  int t = threadIdx.x;
  int per = (n + 1023) >> 10;
  int lo = t * per;
  int hi = lo + per; if (hi > n) hi = n;
  int s = 0;
  for (int i = lo; i < hi; ++i) s += cnt[i];
  lsum[t] = s;
  __syncthreads();
  for (int off = 1; off < 1024; off <<= 1) {
    int v = 0;
    if (t >= off) v = lsum[t - off];
    __syncthreads();
    if (t >= off) lsum[t] += v;
    __syncthreads();
  }
  int run = (t == 0) ? 0 : lsum[t - 1];
  for (int i = lo; i < hi; ++i) {
    int c = cnt[i];
    rowptr[i] = run;
    cnt[i] = run;              // becomes the scatter cursor
    run += c;
  }
  if (t == 1023) rowptr[n] = run;   // = E
}

__global__ void k_scatter(const int* __restrict__ rows, const int* __restrict__ cols,
                          const float* __restrict__ vals, int* __restrict__ cursor,
                          int* __restrict__ scol, float* __restrict__ sval, int E) {
  int e = blockIdx.x * blockDim.x + threadIdx.x;
  if (e >= E) return;
  int r = rows[e];
  int p = atomicAdd(&cursor[r], 1);
  scol[p] = cols[e];
  sval[p] = vals[e];
}

// ---------------- shared epilogue: out[(b,r),ob..ob+7] (+)= y_row @ Wk ----------------
__device__ __forceinline__ void load_w(const float* __restrict__ weight, int km,
                                       float* __restrict__ Wl) {
  for (int idx = threadIdx.x; idx < DDIM * ODIM; idx += blockDim.x) {
    int d = idx >> 6, o = idx & 63;
    Wl[d * W_STRIDE + o] = weight[(d * KM + km) * ODIM + o];
  }
}

__device__ __forceinline__ void row_gemm(int r, int lane, float* __restrict__ yw,
                                         const float* __restrict__ Wl,
                                         float4 a0, float4 a1,
                                         const float* __restrict__ bias,
                                         float* __restrict__ out, bool initMode) {
  const int b = lane >> 3;
  const int dblk = lane & 7;
  float* dst = yw + b * Y_STRIDE + dblk * 8;
  dst[0] = a0.x; dst[1] = a0.y; dst[2] = a0.z; dst[3] = a0.w;
  dst[4] = a1.x; dst[5] = a1.y; dst[6] = a1.z; dst[7] = a1.w;
  __syncthreads();   // also orders the Wl cooperative load before its reads below
  const int ob = dblk * 8;
  const float* yb = yw + b * Y_STRIDE;
  float po0=0.f,po1=0.f,po2=0.f,po3=0.f,po4=0.f,po5=0.f,po6=0.f,po7=0.f;
  #pragma unroll 8
  for (int d = 0; d < DDIM; ++d) {
    float yv = yb[d];
    const float4 w0 = *(const float4*)(Wl + d * W_STRIDE + ob);
    const float4 w1 = *(const float4*)(Wl + d * W_STRIDE + ob + 4);
    po0 = fmaf(yv, w0.x, po0); po1 = fmaf(yv, w0.y, po1);
    po2 = fmaf(yv, w0.z, po2); po3 = fmaf(yv, w0.w, po3);
    po4 = fmaf(yv, w1.x, po4); po5 = fmaf(yv, w1.y, po5);
    po6 = fmaf(yv, w1.z, po6); po7 = fmaf(yv, w1.w, po7);
  }
  float* op = out + ((size_t)b * N_NODES + r) * ODIM + ob;
  if (initMode) {
    float4 b0 = *(const float4*)(bias + ob);
    float4 b1 = *(const float4*)(bias + ob + 4);
    float4 r0 = make_float4(po0 + b0.x, po1 + b0.y, po2 + b0.z, po3 + b0.w);
    float4 r1 = make_float4(po4 + b1.x, po5 + b1.y, po6 + b1.z, po7 + b1.w);
    *(float4*)op = r0;
    *((float4*)op + 1) = r1;
  } else {
    float4 c0 = *(const float4*)op;
    float4 c1 = *((const float4*)op + 1);
    c0.x += po0; c0.y += po1; c0.z += po2; c0.w += po3;
    c1.x += po4; c1.y += po5; c1.z += po6; c1.w += po7;
    *(float4*)op = c0;
    *((float4*)op + 1) = c1;
  }
}

// ---------------- out = bias + x0 @ W0 ----------------
__global__ void __launch_bounds__(256) k_g0(const float* __restrict__ x0,
                                            const float* __restrict__ weight,
                                            const float* __restrict__ bias,
                                            float* __restrict__ out) {
  __shared__ float Wl[DDIM * W_STRIDE];
  __shared__ float yl[4][8 * Y_STRIDE];
  load_w(weight, 0, Wl);
  int wid = threadIdx.x >> 6, lane = threadIdx.x & 63;
  int r = blockIdx.x * 4 + wid;
  const float4* xr = (const float4*)(x0 + (size_t)r * BD + lane * 8);
  float4 a0 = xr[0], a1 = xr[1];
  row_gemm(r, lane, yl[wid], Wl, a0, a1, bias, out, true);
}

// ---------------- SpMM (CSR gather) + fused GEMM epilogue ----------------
// WRITE_X: store y into xout (needed as next diffusion input)
// CHEB:    y = 2*A*xin - xprev
template<bool WRITE_X, bool CHEB>
__global__ void __launch_bounds__(256) k_spmm(const int* __restrict__ rowptr,
                                              const int* __restrict__ scol,
                                              const float* __restrict__ sval,
                                              const float* __restrict__ xin,
                                              float* __restrict__ xout,
                                              const float* __restrict__ xprev,
                                              const float* __restrict__ weight, int km,
                                              const float* __restrict__ bias,
                                              float* __restrict__ out) {
  __shared__ float Wl[DDIM * W_STRIDE];
  __shared__ float yl[4][8 * Y_STRIDE];
  load_w(weight, km, Wl);
  int wid = threadIdx.x >> 6, lane = threadIdx.x & 63;
  int r = blockIdx.x * 4 + wid;          // one wave per row
  int e0 = rowptr[r], e1 = rowptr[r + 1];
  float4 a0 = make_float4(0.f,0.f,0.f,0.f), a1 = make_float4(0.f,0.f,0.f,0.f);
  int col = 0; float val = 0.f;
  if (e0 < e1) { col = scol[e0]; val = sval[e0]; }
  for (int e = e0; e < e1; ++e) {
    int c = col; float v = val;
    if (e + 1 < e1) { col = scol[e + 1]; val = sval[e + 1]; }   // prefetch next edge
    const float4* xr = (const float4*)(xin + (size_t)c * BD + lane * 8);
    float4 u0 = xr[0], u1 = xr[1];
    a0.x = fmaf(v, u0.x, a0.x); a0.y = fmaf(v, u0.y, a0.y);
    a0.z = fmaf(v, u0.z, a0.z); a0.w = fmaf(v, u0.w, a0.w);
    a1.x = fmaf(v, u1.x, a1.x); a1.y = fmaf(v, u1.y, a1.y);
    a1.z = fmaf(v, u1.z, a1.z); a1.w = fmaf(v, u1.w, a1.w);
  }
  if (CHEB) {
    const float4* xp = (const float4*)(xprev + (size_t)r * BD + lane * 8);
    float4 p0 = xp[0], p1 = xp[1];
    a0.x = 2.f*a0.x - p0.x; a0.y = 2.f*a0.y - p0.y;
    a0.z = 2.f*a0.z - p0.z; a0.w = 2.f*a0.w - p0.w;
    a1.x = 2.f*a1.x - p1.x; a1.y = 2.f*a1.y - p1.y;
    a1.z = 2.f*a1.z - p1.z; a1.w = 2.f*a1.w - p1.w;
  }
  if (WRITE_X) {
    float4* xo = (float4*)(xout + (size_t)r * BD + lane * 8);
    xo[0] = a0; xo[1] = a1;
  }
  row_gemm(r, lane, yl[wid], Wl, a0, a1, bias, out, false);
}

// ---------------- launcher ----------------
extern "C" void kernel_launch(void* const* d_in, const int* in_sizes, int n_in,
                              void* d_out, int out_size, void* d_ws, size_t ws_size,
                              hipStream_t stream) {
  const float* x      = (const float*)d_in[0];
  const int*   rows0  = (const int*)d_in[1];
  const int*   cols0  = (const int*)d_in[2];
  const float* vals0  = (const float*)d_in[3];
  const int*   rows1  = (const int*)d_in[4];
  const int*   cols1  = (const int*)d_in[5];
  const float* vals1  = (const float*)d_in[6];
  const float* weight = (const float*)d_in[7];
  const float* bias   = (const float*)d_in[8];
  float* out = (float*)d_out;
  const int E = in_sizes[1];

  char* p = (char*)d_ws;
  auto alloc = [&](size_t bytes) {
    char* q = p;
    p += (bytes + 255) & ~(size_t)255;
    return q;
  };
  float* x0     = (float*)alloc((size_t)N_NODES * BD * sizeof(float));
  float* x1     = (float*)alloc((size_t)N_NODES * BD * sizeof(float));
  int*   rowptr = (int*)alloc((size_t)(N_NODES + 1) * sizeof(int));
  int*   cursor = (int*)alloc((size_t)N_NODES * sizeof(int));
  int*   scol   = (int*)alloc((size_t)E * sizeof(int));
  float* sval   = (float*)alloc((size_t)E * sizeof(float));
  if ((size_t)(p - (char*)d_ws) > ws_size) return;  // workspace too small: bail

  const int tot4 = BDIM * N_NODES * DDIM / 4;
  k_transpose<<<(tot4 + 255) / 256, 256, 0, stream>>>(x, x0, tot4);
  k_g0<<<N_NODES / 4, 256, 0, stream>>>(x0, weight, bias, out);

  for (int m = 0; m < 2; ++m) {
    const int*   rows = m ? rows1 : rows0;
    const int*   cols = m ? cols1 : cols0;
    const float* vals = m ? vals1 : vals0;
    hipMemsetAsync(cursor, 0, (size_t)N_NODES * sizeof(int), stream);
    k_hist<<<(E + 255) / 256, 256, 0, stream>>>(rows, cursor, E);
    k_scan<<<1, 1024, 0, stream>>>(cursor, rowptr, N_NODES);
    k_scatter<<<(E + 255) / 256, 256, 0, stream>>>(rows, cols, vals, cursor, scol, sval, E);
    // x1 = A @ x0 ; out += x1 @ W[k=1+2m]
    k_spmm<true, false><<<N_NODES / 4, 256, 0, stream>>>(
        rowptr, scol, sval, x0, x1, nullptr, weight, 1 + 2 * m, bias, out);
    // y = 2*A @ x1 - x0 ; out += y @ W[k=2+2m]   (y never materialized)
    k_spmm<false, true><<<N_NODES / 4, 256, 0, stream>>>(
        rowptr, scol, sval, x1, nullptr, x0, weight, 2 + 2 * m, bias, out);
  }
}

// Round 2
// 1565.172 us; speedup vs baseline: 1.6544x; 1.6544x over previous
//
#include <hip/hip_runtime.h>

#define N_NODES 50000
#define BDIM 8
#define DDIM 64
#define ODIM 64
#define KM 5
#define BD 512          // B*D
#define W_STRIDE 68     // 64 + 4 pad
#define Y_STRIDE 65     // 64 + 1 pad

typedef unsigned int u32;
typedef unsigned short u16;

__device__ __forceinline__ float bfl(u32 u) { return __uint_as_float(u << 16); }
__device__ __forceinline__ float bfh(u32 u) { return __uint_as_float(u & 0xFFFF0000u); }
__device__ __forceinline__ u32 pack2(float f0, float f1) {
  u32 a = __float_as_uint(f0), b = __float_as_uint(f1);
  u32 ra = (a + 0x7FFFu + ((a >> 16) & 1u)) >> 16;
  u32 rb = (b + 0x7FFFu + ((b >> 16) & 1u)) >> 16;
  return ra | (rb << 16);
}

// ---------------- transpose: x (B,N,D) fp32 -> x0h (N, B*D) bf16 ----------------
__global__ void k_transpose_h(const float* __restrict__ x, u16* __restrict__ x0h, int tot4) {
  int i = blockIdx.x * blockDim.x + threadIdx.x;
  if (i >= tot4) return;
  int f = i << 2;
  int d = f & (DDIM - 1);
  int nb = f >> 6;                // b*N + n
  int b = nb / N_NODES;
  int n = nb - b * N_NODES;
  float4 v = *(const float4*)(x + (size_t)f);
  uint2 w = make_uint2(pack2(v.x, v.y), pack2(v.z, v.w));
  *(uint2*)(x0h + (size_t)n * BD + b * DDIM + d) = w;
}

// ---------------- CSR build (both graphs in one launch) ----------------
__global__ void k_hist2(const int* __restrict__ r0, const int* __restrict__ r1,
                        int* __restrict__ cnt /*2N*/, int E) {
  int i = blockIdx.x * blockDim.x + threadIdx.x;
  if (i < E) atomicAdd(&cnt[r0[i]], 1);
  else atomicAdd(&cnt[N_NODES + r1[i - E]], 1);
}

// grid=2: block g scans cnt[g*N .. g*N+N) in place -> cursor; writes rowptr[g*(N+1)..]
__global__ void k_scan2(int* __restrict__ cnt_all, int* __restrict__ rowptr_all, int n) {
  __shared__ int lsum[1024];
  int* cnt = cnt_all + blockIdx.x * n;
  int* rowptr = rowptr_all + blockIdx.x * (n + 1);
  int t = threadIdx.x;
  int per = (n + 1023) >> 10;
  int lo = t * per;
  int hi = lo + per; if (hi > n) hi = n; if (lo > n) lo = n;
  int s = 0;
  for (int i = lo; i < hi; ++i) s += cnt[i];
  lsum[t] = s;
  __syncthreads();
  for (int off = 1; off < 1024; off <<= 1) {
    int v = 0;
    if (t >= off) v = lsum[t - off];
    __syncthreads();
    if (t >= off) lsum[t] += v;
    __syncthreads();
  }
  int run = (t == 0) ? 0 : lsum[t - 1];
  for (int i = lo; i < hi; ++i) {
    int c = cnt[i];
    rowptr[i] = run;
    cnt[i] = run;
    run += c;
  }
  if (t == 1023) rowptr[n] = run;
}

__global__ void k_scatter2(const int* __restrict__ r0, const int* __restrict__ c0, const float* __restrict__ v0,
                           const int* __restrict__ r1, const int* __restrict__ c1, const float* __restrict__ v1,
                           int* __restrict__ cursor /*2N*/, int* __restrict__ scol /*2E*/,
                           float* __restrict__ sval /*2E*/, int E) {
  int i = blockIdx.x * blockDim.x + threadIdx.x;
  if (i < E) {
    int r = r0[i];
    int p = atomicAdd(&cursor[r], 1);
    scol[p] = c0[i]; sval[p] = v0[i];
  } else {
    int j = i - E;
    int r = r1[j];
    int p = atomicAdd(&cursor[N_NODES + r], 1);
    scol[E + p] = c1[j]; sval[E + p] = v1[j];
  }
}

// ---------------- gather: acc[0..7] = sum_e v * xh[col, lane*8 .. +8] ----------------
__device__ __forceinline__ void fma8(float a[8], uint4 q, float v) {
  a[0] = fmaf(v, bfl(q.x), a[0]); a[1] = fmaf(v, bfh(q.x), a[1]);
  a[2] = fmaf(v, bfl(q.y), a[2]); a[3] = fmaf(v, bfh(q.y), a[3]);
  a[4] = fmaf(v, bfl(q.z), a[4]); a[5] = fmaf(v, bfh(q.z), a[5]);
  a[6] = fmaf(v, bfl(q.w), a[6]); a[7] = fmaf(v, bfh(q.w), a[7]);
}

__device__ __forceinline__ void gather(const int* __restrict__ rp, const int* __restrict__ sc,
                                       const float* __restrict__ sv, const u16* __restrict__ xh,
                                       int r, int lane, float acc[8]) {
  int e0 = rp[r], e1 = rp[r + 1];
  float aA[8] = {0,0,0,0,0,0,0,0};
  float aB[8] = {0,0,0,0,0,0,0,0};
  int e = e0;
  for (; e + 2 <= e1; e += 2) {
    int cA = sc[e], cB = sc[e + 1];
    float vA = sv[e], vB = sv[e + 1];
    uint4 qA = *(const uint4*)(xh + (size_t)cA * BD + lane * 8);
    uint4 qB = *(const uint4*)(xh + (size_t)cB * BD + lane * 8);
    fma8(aA, qA, vA);
    fma8(aB, qB, vB);
  }
  if (e < e1) {
    int c = sc[e]; float v = sv[e];
    uint4 q = *(const uint4*)(xh + (size_t)c * BD + lane * 8);
    fma8(aA, q, v);
  }
  #pragma unroll
  for (int j = 0; j < 8; ++j) acc[j] = aA[j] + aB[j];
}

// ---------------- epilogue pass: po += y_row @ W[:,km,:] ----------------
__device__ __forceinline__ void load_w(const float* __restrict__ weight, int km,
                                       float* __restrict__ Wl) {
  for (int idx = threadIdx.x; idx < DDIM * ODIM; idx += blockDim.x) {
    int d = idx >> 6, o = idx & 63;
    Wl[d * W_STRIDE + o] = weight[(d * KM + km) * ODIM + o];
  }
}

__device__ __forceinline__ void epi_pass(int lane, float* __restrict__ yw,
                                         float* __restrict__ Wl,
                                         const float* __restrict__ weight, int km,
                                         const float a[8], float po[8]) {
  __syncthreads();   // previous pass's reads of yw/Wl complete
  const int b = lane >> 3;
  const int dblk = lane & 7;
  float* dst = yw + b * Y_STRIDE + dblk * 8;
  #pragma unroll
  for (int j = 0; j < 8; ++j) dst[j] = a[j];
  load_w(weight, km, Wl);
  __syncthreads();
  const int ob = dblk * 8;
  const float* yb = yw + b * Y_STRIDE;
  #pragma unroll 8
  for (int d = 0; d < DDIM; ++d) {
    float yv = yb[d];
    const float4 w0 = *(const float4*)(Wl + d * W_STRIDE + ob);
    const float4 w1 = *(const float4*)(Wl + d * W_STRIDE + ob + 4);
    po[0] = fmaf(yv, w0.x, po[0]); po[1] = fmaf(yv, w0.y, po[1]);
    po[2] = fmaf(yv, w0.z, po[2]); po[3] = fmaf(yv, w0.w, po[3]);
    po[4] = fmaf(yv, w1.x, po[4]); po[5] = fmaf(yv, w1.y, po[5]);
    po[6] = fmaf(yv, w1.z, po[6]); po[7] = fmaf(yv, w1.w, po[7]);
  }
}

// ---------------- hop 1: self(k=0) + A0*x0(k=1) + A1*x0(k=3); writes x1h's + out ----------------
__global__ void __launch_bounds__(256) k_hop1(const int* __restrict__ rowptr /*2(N+1)*/,
                                              const int* __restrict__ scol /*2E*/,
                                              const float* __restrict__ sval /*2E*/,
                                              const u16* __restrict__ x0h,
                                              u16* __restrict__ x1_0h, u16* __restrict__ x1_1h,
                                              const float* __restrict__ weight,
                                              const float* __restrict__ bias,
                                              float* __restrict__ out, int E) {
  __shared__ float Wl[DDIM * W_STRIDE];
  __shared__ float yl[4][8 * Y_STRIDE];
  int wid = threadIdx.x >> 6, lane = threadIdx.x & 63;
  int r = blockIdx.x * 4 + wid;

  float self[8];
  {
    uint4 q = *(const uint4*)(x0h + (size_t)r * BD + lane * 8);
    self[0] = bfl(q.x); self[1] = bfh(q.x); self[2] = bfl(q.y); self[3] = bfh(q.y);
    self[4] = bfl(q.z); self[5] = bfh(q.z); self[6] = bfl(q.w); self[7] = bfh(q.w);
  }
  float a0[8], a1[8];
  gather(rowptr, scol, sval, x0h, r, lane, a0);
  gather(rowptr + (N_NODES + 1), scol + E, sval + E, x0h, r, lane, a1);

  // store next diffusion inputs (bf16)
  {
    uint4 s0 = make_uint4(pack2(a0[0],a0[1]), pack2(a0[2],a0[3]), pack2(a0[4],a0[5]), pack2(a0[6],a0[7]));
    uint4 s1 = make_uint4(pack2(a1[0],a1[1]), pack2(a1[2],a1[3]), pack2(a1[4],a1[5]), pack2(a1[6],a1[7]));
    *(uint4*)(x1_0h + (size_t)r * BD + lane * 8) = s0;
    *(uint4*)(x1_1h + (size_t)r * BD + lane * 8) = s1;
  }

  const int ob = (lane & 7) * 8;
  float po[8];
  {
    float4 b0 = *(const float4*)(bias + ob);
    float4 b1 = *(const float4*)(bias + ob + 4);
    po[0]=b0.x; po[1]=b0.y; po[2]=b0.z; po[3]=b0.w;
    po[4]=b1.x; po[5]=b1.y; po[6]=b1.z; po[7]=b1.w;
  }
  epi_pass(lane, yl[wid], Wl, weight, 0, self, po);
  epi_pass(lane, yl[wid], Wl, weight, 1, a0, po);
  epi_pass(lane, yl[wid], Wl, weight, 3, a1, po);

  const int b = lane >> 3;
  float* op = out + ((size_t)b * N_NODES + r) * ODIM + ob;
  *(float4*)op = make_float4(po[0], po[1], po[2], po[3]);
  *((float4*)op + 1) = make_float4(po[4], po[5], po[6], po[7]);
}

// ---------------- hop 2: (2*A0*x1_0 - x0)(k=2) + (2*A1*x1_1 - x0)(k=4); out += ----------------
__global__ void __launch_bounds__(256) k_hop2(const int* __restrict__ rowptr,
                                              const int* __restrict__ scol,
                                              const float* __restrict__ sval,
                                              const u16* __restrict__ x0h,
                                              const u16* __restrict__ x1_0h,
                                              const u16* __restrict__ x1_1h,
                                              const float* __restrict__ weight,
                                              float* __restrict__ out, int E) {
  __shared__ float Wl[DDIM * W_STRIDE];
  __shared__ float yl[4][8 * Y_STRIDE];
  int wid = threadIdx.x >> 6, lane = threadIdx.x & 63;
  int r = blockIdx.x * 4 + wid;

  float p[8];
  {
    uint4 q = *(const uint4*)(x0h + (size_t)r * BD + lane * 8);
    p[0] = bfl(q.x); p[1] = bfh(q.x); p[2] = bfl(q.y); p[3] = bfh(q.y);
    p[4] = bfl(q.z); p[5] = bfh(q.z); p[6] = bfl(q.w); p[7] = bfh(q.w);
  }
  float b0[8], b1[8];
  gather(rowptr, scol, sval, x1_0h, r, lane, b0);
  gather(rowptr + (N_NODES + 1), scol + E, sval + E, x1_1h, r, lane, b1);
  #pragma unroll
  for (int j = 0; j < 8; ++j) {
    b0[j] = 2.f * b0[j] - p[j];
    b1[j] = 2.f * b1[j] - p[j];
  }

  float po[8] = {0,0,0,0,0,0,0,0};
  epi_pass(lane, yl[wid], Wl, weight, 2, b0, po);
  epi_pass(lane, yl[wid], Wl, weight, 4, b1, po);

  const int b = lane >> 3;
  const int ob = (lane & 7) * 8;
  float* op = out + ((size_t)b * N_NODES + r) * ODIM + ob;
  float4 c0 = *(const float4*)op;
  float4 c1 = *((const float4*)op + 1);
  c0.x += po[0]; c0.y += po[1]; c0.z += po[2]; c0.w += po[3];
  c1.x += po[4]; c1.y += po[5]; c1.z += po[6]; c1.w += po[7];
  *(float4*)op = c0;
  *((float4*)op + 1) = c1;
}

// ---------------- launcher ----------------
extern "C" void kernel_launch(void* const* d_in, const int* in_sizes, int n_in,
                              void* d_out, int out_size, void* d_ws, size_t ws_size,
                              hipStream_t stream) {
  const float* x      = (const float*)d_in[0];
  const int*   rows0  = (const int*)d_in[1];
  const int*   cols0  = (const int*)d_in[2];
  const float* vals0  = (const float*)d_in[3];
  const int*   rows1  = (const int*)d_in[4];
  const int*   cols1  = (const int*)d_in[5];
  const float* vals1  = (const float*)d_in[6];
  const float* weight = (const float*)d_in[7];
  const float* bias   = (const float*)d_in[8];
  float* out = (float*)d_out;
  const int E = in_sizes[1];

  char* p = (char*)d_ws;
  auto alloc = [&](size_t bytes) {
    char* q = p;
    p += (bytes + 255) & ~(size_t)255;
    return q;
  };
  u16*   x0h    = (u16*)alloc((size_t)N_NODES * BD * sizeof(u16));
  u16*   x1_0h  = (u16*)alloc((size_t)N_NODES * BD * sizeof(u16));
  u16*   x1_1h  = (u16*)alloc((size_t)N_NODES * BD * sizeof(u16));
  int*   rowptr = (int*)alloc((size_t)2 * (N_NODES + 1) * sizeof(int));
  int*   cursor = (int*)alloc((size_t)2 * N_NODES * sizeof(int));
  int*   scol   = (int*)alloc((size_t)2 * E * sizeof(int));
  float* sval   = (float*)alloc((size_t)2 * E * sizeof(float));
  if ((size_t)(p - (char*)d_ws) > ws_size) return;

  const int tot4 = BDIM * N_NODES * DDIM / 4;
  k_transpose_h<<<(tot4 + 255) / 256, 256, 0, stream>>>(x, x0h, tot4);

  hipMemsetAsync(cursor, 0, (size_t)2 * N_NODES * sizeof(int), stream);
  k_hist2<<<(2 * E + 255) / 256, 256, 0, stream>>>(rows0, rows1, cursor, E);
  k_scan2<<<2, 1024, 0, stream>>>(cursor, rowptr, N_NODES);
  k_scatter2<<<(2 * E + 255) / 256, 256, 0, stream>>>(rows0, cols0, vals0,
                                                      rows1, cols1, vals1,
                                                      cursor, scol, sval, E);

  k_hop1<<<N_NODES / 4, 256, 0, stream>>>(rowptr, scol, sval, x0h, x1_0h, x1_1h,
                                          weight, bias, out, E);
  k_hop2<<<N_NODES / 4, 256, 0, stream>>>(rowptr, scol, sval, x0h, x1_0h, x1_1h,
                                          weight, out, E);
}